// Round 18
// baseline (80.728 us; speedup 1.0000x reference)
//
#include <hip/hip_runtime.h>
#include <stdint.h>

#define NB    128
#define NSTEP 63
#define DT    0.00390625f
#define TSC   2.8853900817779268f   // 2*log2(e): folded into GEMM1 weights

typedef __attribute__((ext_vector_type(8))) short bf16x8;
typedef __attribute__((ext_vector_type(4))) float f32x4;
typedef __attribute__((ext_vector_type(2))) float f32x2;

union Frag { bf16x8 v; uint32_t u[4]; };

__device__ __forceinline__ short f2bf(float f) {
    uint32_t u = __float_as_uint(f);
    u += 0x7FFF + ((u >> 16) & 1);          // round-to-nearest-even
    return (short)(u >> 16);
}

__device__ __forceinline__ uint32_t pk_bf16(float lo, float hi) {
    uint32_t r;
    asm("v_cvt_pk_bf16_f32 %0, %1, %2" : "=v"(r) : "v"(lo), "v"(hi));
    return r;
}

// PAIRED u-activation: u_i = 1/(2^y_i + 1), two values sharing ONE rcp via
// r = rcp(d0*d1); u0 = r*d1, u1 = r*d0.  3 TRANS + 3 VALU per pair instead
// of 4 TRANS + 1 VALU: -8 TRANS/lane-step (TRANS is the largest pipe term:
// 1024 of 1824 busy cyc/SIMD-step; VALUBusy counter includes TRANS).
// Precision: rcp rel-err ~1e-7 + one extra rounding ~2e-7, far below the
// bf16 pack quantization (4e-3). Builtins only (inline-asm exp broke R3).
__device__ __forceinline__ f32x2 sig_u2(float y0, float y1) {
    f32x2 e = { __builtin_amdgcn_exp2f(y0), __builtin_amdgcn_exp2f(y1) };
    f32x2 d = e + (f32x2)1.0f;                      // v_pk_add
    const float p = d.x * d.y;                      // v_mul
    const float r = __builtin_amdgcn_rcpf(p);       // one rcp per pair
    return (f32x2){r, r} * (f32x2){d.y, d.x};       // v_pk_mul
}

// R17 (76.7 us, best) + rcp-paired activation. Everything else identical:
// 4 waves/block x 1024 blocks, net-per-wave decomposition, u-fold diet
// (W2' = -2*W2, C-in = B2 + sum_h W2 via 2 init MFMAs), conflict-free
// striped exchange, noise LDS-staged transposed, independent GEMM2 MFMAs,
// bias advance in barrier shadow.
__global__ __launch_bounds__(256, 4) void sde_rcp2(
    const float* __restrict__ x_real, const float* __restrict__ x_imag,
    const float* __restrict__ params, const float* __restrict__ noise,
    const float* __restrict__ W1, const float* __restrict__ B1,
    const float* __restrict__ W2, const float* __restrict__ B2,
    float* __restrict__ out)
{
    __shared__ f32x4 xbuf4[2][16][16];   // [dbuf][row=net*4+dim4][traj]
    __shared__ float nl[64 * 16];        // [step][traj], row 63 = row 62

    const int tid  = threadIdx.x;
    const int lane = tid & 63;
    const int l15  = lane & 15;
    const int g    = lane >> 4;
    const int wv   = tid >> 6;          // net index 0..3

    // ---- stage noise: 1008 contiguous floats -> transposed LDS ----
    {
        const float* __restrict__ nb = noise + (size_t)(blockIdx.x * 16) * NSTEP;
        #pragma unroll
        for (int k = 0; k < 4; ++k) {
            const int idx = tid + k * 256;
            if (idx < 16 * NSTEP) {
                const int traj = (idx * 4162) >> 18;     // idx/63 (magic)
                const int s    = idx - traj * 63;
                nl[s * 16 + traj] = nb[idx];
            }
        }
    }

    // ---- GEMM1 A-frags: tile t, row=l15 -> h = 16t + l15 (within net wv),
    //      elem j -> state feature 8g + j; pre-scaled by TSC ----
    Frag w1f[4];
    #pragma unroll
    for (int t = 0; t < 4; ++t) {
        const int h = 16 * t + l15;
        #pragma unroll
        for (int j = 0; j < 8; ++j)
            w1f[t].v[j] = f2bf(TSC * W1[(wv * 38 + 1 + 8 * g + j) * 64 + h]);
    }

    // ---- GEMM2 A-frags (W2' = -2*W2): row=l15=d,
    //      elem j -> h_local = 16*(2kt+(j>>2)) + 4g + (j&3) ----
    Frag w2f[2];
    #pragma unroll
    for (int kt = 0; kt < 2; ++kt) {
        #pragma unroll
        for (int j = 0; j < 8; ++j) {
            const int hl = 16 * (2 * kt + (j >> 2)) + 4 * g + (j & 3);
            w2f[kt].v[j] = f2bf(-2.0f * W2[(wv * 64 + hl) * 16 + l15]);
        }
    }

    // ---- bias + t-coefficient at C-layout positions (scaled by TSC) ----
    float pr[5];
    #pragma unroll
    for (int p = 0; p < 5; ++p) pr[p] = params[p];
    f32x4 biascur[4], wtdt[4];
    #pragma unroll
    for (int t = 0; t < 4; ++t) {
        #pragma unroll
        for (int r = 0; r < 4; ++r) {
            const int h = 16 * t + 4 * g + r;
            float b = B1[wv * 64 + h];
            #pragma unroll
            for (int p = 0; p < 5; ++p)
                b = fmaf(pr[p], W1[(wv * 38 + 33 + p) * 64 + h], b);
            biascur[t][r] = TSC * b;
            wtdt[t][r]    = (TSC * DT) * W1[(wv * 38 + 0) * 64 + h];
        }
    }

    // ---- GEMM2 C-in': B2 + sum_h W2[h, d] via 2 MFMAs with B-frag -0.5 ----
    f32x4 bc;
    #pragma unroll
    for (int r = 0; r < 4; ++r) bc[r] = B2[wv * 16 + 4 * g + r];
    {
        Frag nh;
        nh.u[0] = 0xBF00BF00u;  nh.u[1] = 0xBF00BF00u;   // bf16 -0.5 x2
        nh.u[2] = 0xBF00BF00u;  nh.u[3] = 0xBF00BF00u;
        bc = __builtin_amdgcn_mfma_f32_16x16x32_bf16(w2f[0].v, nh.v, bc, 0, 0, 0);
        bc = __builtin_amdgcn_mfma_f32_16x16x32_bf16(w2f[1].v, nh.v, bc, 0, 0, 0);
    }

    // ---- state: lane holds comps 8g..8g+7 of traj n (replicated across waves) ----
    const int n    = blockIdx.x * 16 + l15;
    const int xrow = n & (NB - 1);
    const float* __restrict__ xsrc = (g < 2) ? x_real : x_imag;
    const int xoff = (g & 1) * 8;
    f32x4 stlo = *reinterpret_cast<const f32x4*>(&xsrc[xrow * 16 + xoff]);
    f32x4 sthi = *reinterpret_cast<const f32x4*>(&xsrc[xrow * 16 + xoff + 4]);

    __syncthreads();                    // noise staging visible
    if (tid < 16) nl[63 * 16 + tid] = nl[62 * 16 + tid];
    __syncthreads();                    // row-63 fill visible

    float dw = nl[l15];                 // step 0

    // exchange rows: write wv*4+g; read net*4 + 2*(g&1) (+1), nets g>>1, 2+(g>>1)
    const int wrow  = wv * 4 + g;
    const int r_dr  = (g >> 1) * 4 + 2 * (g & 1);
    const int r_df  = (2 + (g >> 1)) * 4 + 2 * (g & 1);
    const f32x4 zer4 = (f32x4)0.0f;

    for (int s = 0; s < NSTEP; ++s) {
        const float dwn = nl[(s + 1) * 16 + l15];   // row 63 = row 62 copy

        // state -> bf16 B-fragment (k-slot 8g+j = component 8g+j)
        Frag bx;
        bx.u[0] = pk_bf16(stlo[0], stlo[1]);
        bx.u[1] = pk_bf16(stlo[2], stlo[3]);
        bx.u[2] = pk_bf16(sthi[0], sthi[1]);
        bx.u[3] = pk_bf16(sthi[2], sthi[3]);

        // GEMM1: 4 MFMAs, C-in = scaled bias + t*w_t
        f32x4 acc[4];
        #pragma unroll
        for (int t = 0; t < 4; ++t)
            acc[t] = __builtin_amdgcn_mfma_f32_16x16x32_bf16(
                w1f[t].v, bx.v, biascur[t], 0, 0, 0);

        // paired u-activation (one rcp per pair; pairs = pk_bf16 pairs)
        f32x2 u01 = sig_u2(acc[0][0], acc[0][1]);
        f32x2 u23 = sig_u2(acc[0][2], acc[0][3]);
        f32x2 u45 = sig_u2(acc[1][0], acc[1][1]);
        f32x2 u67 = sig_u2(acc[1][2], acc[1][3]);
        f32x2 u89 = sig_u2(acc[2][0], acc[2][1]);
        f32x2 uAB = sig_u2(acc[2][2], acc[2][3]);
        f32x2 uCD = sig_u2(acc[3][0], acc[3][1]);
        f32x2 uEF = sig_u2(acc[3][2], acc[3][3]);

        // GEMM2: two INDEPENDENT MFMAs (o0 from bc, o1 from 0), add at write
        Frag pb0, pb1;
        pb0.u[0] = pk_bf16(u01.x, u01.y);  pb0.u[1] = pk_bf16(u23.x, u23.y);
        pb0.u[2] = pk_bf16(u45.x, u45.y);  pb0.u[3] = pk_bf16(u67.x, u67.y);
        pb1.u[0] = pk_bf16(u89.x, u89.y);  pb1.u[1] = pk_bf16(uAB.x, uAB.y);
        pb1.u[2] = pk_bf16(uCD.x, uCD.y);  pb1.u[3] = pk_bf16(uEF.x, uEF.y);
        const f32x4 o0 = __builtin_amdgcn_mfma_f32_16x16x32_bf16(
            w2f[0].v, pb0.v, bc, 0, 0, 0);
        const f32x4 o1 = __builtin_amdgcn_mfma_f32_16x16x32_bf16(
            w2f[1].v, pb1.v, zer4, 0, 0, 0);

        // ---- exchange: conflict-free consecutive-lane layout ----
        const int db = s & 1;
        xbuf4[db][wrow][l15] = o0 + o1;
        // bias advance in the barrier shadow
        #pragma unroll
        for (int t = 0; t < 4; ++t) biascur[t] += wtdt[t];
        __syncthreads();
        const f32x4 dr0 = xbuf4[db][r_dr][l15];
        const f32x4 dr1 = xbuf4[db][r_dr + 1][l15];
        const f32x4 df0 = xbuf4[db][r_df][l15];
        const f32x4 df1 = xbuf4[db][r_df + 1][l15];

        // Euler-Maruyama, packed v_pk_fma
        const f32x4 dt4 = (f32x4)DT;
        const f32x4 dw4 = (f32x4)dw;
        stlo = __builtin_elementwise_fma(dt4, dr0,
               __builtin_elementwise_fma(dw4, df0, stlo));
        sthi = __builtin_elementwise_fma(dt4, dr1,
               __builtin_elementwise_fma(dw4, df1, sthi));
        dw = dwn;
    }

    // ---- write out (wave 0 only): lane holds comps 8g..8g+7 of traj n ----
    if (wv == 0) {
        float4* op = reinterpret_cast<float4*>(out + (size_t)n * 32 + 8 * g);
        op[0] = make_float4(stlo[0], stlo[1], stlo[2], stlo[3]);
        op[1] = make_float4(sthi[0], sthi[1], sthi[2], sthi[3]);
    }
}

extern "C" void kernel_launch(void* const* d_in, const int* in_sizes, int n_in,
                              void* d_out, int out_size, void* d_ws, size_t ws_size,
                              hipStream_t stream) {
    const float* x_real = (const float*)d_in[0];
    const float* x_imag = (const float*)d_in[1];
    const float* params = (const float*)d_in[2];
    const float* noise  = (const float*)d_in[3];
    const float* W1     = (const float*)d_in[4];
    const float* B1     = (const float*)d_in[5];
    const float* W2     = (const float*)d_in[6];
    const float* B2     = (const float*)d_in[7];
    float* out = (float*)d_out;

    // 1024 blocks x 256 threads: 4 waves/block, one 16-traj group per block
    sde_rcp2<<<dim3(1024), dim3(256), 0, stream>>>(
        x_real, x_imag, params, noise, W1, B1, W2, B2, out);
}

// Round 20
// 76.613 us; speedup vs baseline: 1.0537x; 1.0537x over previous
//
#include <hip/hip_runtime.h>
#include <stdint.h>

#define NB    128
#define NSTEP 63
#define DT    0.00390625f
#define TSC   2.8853900817779268f   // 2*log2(e): folded into GEMM1 weights

typedef __attribute__((ext_vector_type(8))) short bf16x8;
typedef __attribute__((ext_vector_type(4))) float f32x4;

union Frag { bf16x8 v; uint32_t u[4]; };

__device__ __forceinline__ short f2bf(float f) {
    uint32_t u = __float_as_uint(f);
    u += 0x7FFF + ((u >> 16) & 1);          // round-to-nearest-even
    return (short)(u >> 16);
}

__device__ __forceinline__ uint32_t pk_bf16(float lo, float hi) {
    uint32_t r;
    asm("v_cvt_pk_bf16_f32 %0, %1, %2" : "=v"(r) : "v"(lo), "v"(hi));
    return r;
}

// u = 1/(2^y + 1) with y = 2*log2e*preact (TSC folded into GEMM1 weights).
// tanh = 1 - 2u; affine part folded into GEMM2 (W2' = -2*W2, C-in' = B2 +
// sum_h W2[h,:] via 2 init MFMAs). Independent exp/rcp chains (R18's
// shared-rcp pairing lengthened the critical path and regressed).
// Builtins only (inline-asm exp broke R3).
__device__ __forceinline__ float sig_u(float y) {
    float e = __builtin_amdgcn_exp2f(y);
    return __builtin_amdgcn_rcpf(e + 1.0f);
}

// FINAL = R17 (best proven: 76.7 us, 10.2x over the scalar baseline).
// Structure: 4 waves/block x 1024 blocks, one 16-trajectory group/block,
// wave wv owns net wv. GEMM1 swapped (4 MFMAs, 64 h-cols), batched
// u-activation (16 independent TRANS chains), GEMM2 as two INDEPENDENT
// MFMAs (o0 from bc, o1 from 0) + packed add. Conflict-free striped LDS
// exchange (write row wv*4+g, consecutive lanes), double-buffered, one
// barrier/step; bias advance in the barrier shadow. Noise LDS-staged
// transposed once per block (kills the 16-cacheline/step scatter).
// R19's zero-barrier variant NaN'd (cause unidentified); reverted.
__global__ __launch_bounds__(256, 4) void sde_final(
    const float* __restrict__ x_real, const float* __restrict__ x_imag,
    const float* __restrict__ params, const float* __restrict__ noise,
    const float* __restrict__ W1, const float* __restrict__ B1,
    const float* __restrict__ W2, const float* __restrict__ B2,
    float* __restrict__ out)
{
    __shared__ f32x4 xbuf4[2][16][16];   // [dbuf][row=net*4+dim4][traj]
    __shared__ float nl[64 * 16];        // [step][traj], row 63 = row 62

    const int tid  = threadIdx.x;
    const int lane = tid & 63;
    const int l15  = lane & 15;
    const int g    = lane >> 4;
    const int wv   = tid >> 6;          // net index 0..3

    // ---- stage noise: 1008 contiguous floats -> transposed LDS ----
    {
        const float* __restrict__ nb = noise + (size_t)(blockIdx.x * 16) * NSTEP;
        #pragma unroll
        for (int k = 0; k < 4; ++k) {
            const int idx = tid + k * 256;
            if (idx < 16 * NSTEP) {
                const int traj = (idx * 4162) >> 18;     // idx/63 (magic)
                const int s    = idx - traj * 63;
                nl[s * 16 + traj] = nb[idx];
            }
        }
    }

    // ---- GEMM1 A-frags: tile t, row=l15 -> h = 16t + l15 (within net wv),
    //      elem j -> state feature 8g + j; pre-scaled by TSC ----
    Frag w1f[4];
    #pragma unroll
    for (int t = 0; t < 4; ++t) {
        const int h = 16 * t + l15;
        #pragma unroll
        for (int j = 0; j < 8; ++j)
            w1f[t].v[j] = f2bf(TSC * W1[(wv * 38 + 1 + 8 * g + j) * 64 + h]);
    }

    // ---- GEMM2 A-frags (W2' = -2*W2): row=l15=d,
    //      elem j -> h_local = 16*(2kt+(j>>2)) + 4g + (j&3) ----
    Frag w2f[2];
    #pragma unroll
    for (int kt = 0; kt < 2; ++kt) {
        #pragma unroll
        for (int j = 0; j < 8; ++j) {
            const int hl = 16 * (2 * kt + (j >> 2)) + 4 * g + (j & 3);
            w2f[kt].v[j] = f2bf(-2.0f * W2[(wv * 64 + hl) * 16 + l15]);
        }
    }

    // ---- bias + t-coefficient at C-layout positions (scaled by TSC) ----
    float pr[5];
    #pragma unroll
    for (int p = 0; p < 5; ++p) pr[p] = params[p];
    f32x4 biascur[4], wtdt[4];
    #pragma unroll
    for (int t = 0; t < 4; ++t) {
        #pragma unroll
        for (int r = 0; r < 4; ++r) {
            const int h = 16 * t + 4 * g + r;
            float b = B1[wv * 64 + h];
            #pragma unroll
            for (int p = 0; p < 5; ++p)
                b = fmaf(pr[p], W1[(wv * 38 + 33 + p) * 64 + h], b);
            biascur[t][r] = TSC * b;
            wtdt[t][r]    = (TSC * DT) * W1[(wv * 38 + 0) * 64 + h];
        }
    }

    // ---- GEMM2 C-in': B2 + sum_h W2[h, d] via 2 MFMAs with B-frag -0.5 ----
    f32x4 bc;
    #pragma unroll
    for (int r = 0; r < 4; ++r) bc[r] = B2[wv * 16 + 4 * g + r];
    {
        Frag nh;
        nh.u[0] = 0xBF00BF00u;  nh.u[1] = 0xBF00BF00u;   // bf16 -0.5 x2
        nh.u[2] = 0xBF00BF00u;  nh.u[3] = 0xBF00BF00u;
        bc = __builtin_amdgcn_mfma_f32_16x16x32_bf16(w2f[0].v, nh.v, bc, 0, 0, 0);
        bc = __builtin_amdgcn_mfma_f32_16x16x32_bf16(w2f[1].v, nh.v, bc, 0, 0, 0);
    }

    // ---- state: lane holds comps 8g..8g+7 of traj n (replicated across waves) ----
    const int n    = blockIdx.x * 16 + l15;
    const int xrow = n & (NB - 1);
    const float* __restrict__ xsrc = (g < 2) ? x_real : x_imag;
    const int xoff = (g & 1) * 8;
    f32x4 stlo = *reinterpret_cast<const f32x4*>(&xsrc[xrow * 16 + xoff]);
    f32x4 sthi = *reinterpret_cast<const f32x4*>(&xsrc[xrow * 16 + xoff + 4]);

    __syncthreads();                    // noise staging visible
    if (tid < 16) nl[63 * 16 + tid] = nl[62 * 16 + tid];
    __syncthreads();                    // row-63 fill visible

    float dw = nl[l15];                 // step 0

    // exchange rows: write wv*4+g; read net*4 + 2*(g&1) (+1), nets g>>1, 2+(g>>1)
    const int wrow  = wv * 4 + g;
    const int r_dr  = (g >> 1) * 4 + 2 * (g & 1);
    const int r_df  = (2 + (g >> 1)) * 4 + 2 * (g & 1);
    const f32x4 zer4 = (f32x4)0.0f;

    for (int s = 0; s < NSTEP; ++s) {
        const float dwn = nl[(s + 1) * 16 + l15];   // row 63 = row 62 copy

        // state -> bf16 B-fragment (k-slot 8g+j = component 8g+j)
        Frag bx;
        bx.u[0] = pk_bf16(stlo[0], stlo[1]);
        bx.u[1] = pk_bf16(stlo[2], stlo[3]);
        bx.u[2] = pk_bf16(sthi[0], sthi[1]);
        bx.u[3] = pk_bf16(sthi[2], sthi[3]);

        // GEMM1: 4 MFMAs, C-in = scaled bias + t*w_t
        f32x4 acc[4];
        #pragma unroll
        for (int t = 0; t < 4; ++t)
            acc[t] = __builtin_amdgcn_mfma_f32_16x16x32_bf16(
                w1f[t].v, bx.v, biascur[t], 0, 0, 0);

        // all 16 u-activations batched (full-depth TRANS pipelining)
        float uv[16];
        #pragma unroll
        for (int t = 0; t < 4; ++t) {
            uv[4 * t + 0] = sig_u(acc[t][0]);
            uv[4 * t + 1] = sig_u(acc[t][1]);
            uv[4 * t + 2] = sig_u(acc[t][2]);
            uv[4 * t + 3] = sig_u(acc[t][3]);
        }

        // GEMM2: two INDEPENDENT MFMAs (o0 from bc, o1 from 0), add at write
        Frag pb0, pb1;
        pb0.u[0] = pk_bf16(uv[0],  uv[1]);   pb0.u[1] = pk_bf16(uv[2],  uv[3]);
        pb0.u[2] = pk_bf16(uv[4],  uv[5]);   pb0.u[3] = pk_bf16(uv[6],  uv[7]);
        pb1.u[0] = pk_bf16(uv[8],  uv[9]);   pb1.u[1] = pk_bf16(uv[10], uv[11]);
        pb1.u[2] = pk_bf16(uv[12], uv[13]);  pb1.u[3] = pk_bf16(uv[14], uv[15]);
        const f32x4 o0 = __builtin_amdgcn_mfma_f32_16x16x32_bf16(
            w2f[0].v, pb0.v, bc, 0, 0, 0);
        const f32x4 o1 = __builtin_amdgcn_mfma_f32_16x16x32_bf16(
            w2f[1].v, pb1.v, zer4, 0, 0, 0);

        // ---- exchange: conflict-free consecutive-lane layout ----
        const int db = s & 1;
        xbuf4[db][wrow][l15] = o0 + o1;
        // bias advance in the barrier shadow
        #pragma unroll
        for (int t = 0; t < 4; ++t) biascur[t] += wtdt[t];
        __syncthreads();
        const f32x4 dr0 = xbuf4[db][r_dr][l15];
        const f32x4 dr1 = xbuf4[db][r_dr + 1][l15];
        const f32x4 df0 = xbuf4[db][r_df][l15];
        const f32x4 df1 = xbuf4[db][r_df + 1][l15];

        // Euler-Maruyama, packed v_pk_fma
        const f32x4 dt4 = (f32x4)DT;
        const f32x4 dw4 = (f32x4)dw;
        stlo = __builtin_elementwise_fma(dt4, dr0,
               __builtin_elementwise_fma(dw4, df0, stlo));
        sthi = __builtin_elementwise_fma(dt4, dr1,
               __builtin_elementwise_fma(dw4, df1, sthi));
        dw = dwn;
    }

    // ---- write out (wave 0 only): lane holds comps 8g..8g+7 of traj n ----
    if (wv == 0) {
        float4* op = reinterpret_cast<float4*>(out + (size_t)n * 32 + 8 * g);
        op[0] = make_float4(stlo[0], stlo[1], stlo[2], stlo[3]);
        op[1] = make_float4(sthi[0], sthi[1], sthi[2], sthi[3]);
    }
}

extern "C" void kernel_launch(void* const* d_in, const int* in_sizes, int n_in,
                              void* d_out, int out_size, void* d_ws, size_t ws_size,
                              hipStream_t stream) {
    const float* x_real = (const float*)d_in[0];
    const float* x_imag = (const float*)d_in[1];
    const float* params = (const float*)d_in[2];
    const float* noise  = (const float*)d_in[3];
    const float* W1     = (const float*)d_in[4];
    const float* B1     = (const float*)d_in[5];
    const float* W2     = (const float*)d_in[6];
    const float* B2     = (const float*)d_in[7];
    float* out = (float*)d_out;

    // 1024 blocks x 256 threads: 4 waves/block, one 16-traj group per block
    sde_final<<<dim3(1024), dim3(256), 0, stream>>>(
        x_real, x_imag, params, noise, W1, B1, W2, B2, out);
}